// Round 8
// baseline (66.032 us; speedup 1.0000x reference)
//
#include <hip/hip_runtime.h>
#include <hip/hip_bf16.h>

// Framing op: x [16, 1048576] f32 -> out [16, 2048, 2048] f32
// out[b, f, t] = (f*512 + t >= 1536) ? x[b, f*512 + t - 1536] : 0.0f
//
// LDS-STAGED, COARSE-BATCH. One block = 32 consecutive frames of one batch
// = 16384 contiguous f4 (256 KB) of output; 512 threads.
//  Phase 1: stage input window 4480 f4 = 70 KB into LDS (one long read
//    burst; halo amp only 1.09x -> ~73 MB total reads).
//  Phase 2: emit 256 KB as one long, perfectly sequential write burst.
// Rationale (round-7 data): two different minimal-traffic structures both
// plateaued at ~5.2 TB/s vs the 6.3 TB/s copy ceiling. Hypothesis: fine-
// grained read/write interleave at the HBM channels costs ~20% in bus
// turnarounds. Coarse per-block bursts (70 KB read, then 256 KB write),
// with 2 resident blocks/CU pipelining read-phase vs write-phase, restore
// long same-direction bursts per stream.
// LDS 70 KB -> 2 blocks/CU (140 KB < 160 KB), 16 waves/CU.
// Traffic: 268 MB write + 73 MB read = 341 MB -> 54 us at 6.3 TB/s.

typedef float f4 __attribute__((ext_vector_type(4)));

#define T4_PER_B   262144u   // f4 per batch row of x (1048576/4)
#define PREFIX4    384       // 1536 floats / 4 (zero prefix)
#define FRAMES_PB  32u       // frames per block
#define WIN4       4480     // (32-1)*128 + 512 f4 input window
#define OUT4_PB    16384u    // 32 * 512 f4 output per block

__global__ __launch_bounds__(512) void frame_lds32(
    const f4* __restrict__ x4, f4* __restrict__ out4)
{
    __shared__ f4 lds[WIN4];
    const unsigned fg  = blockIdx.x;     // frame group 0..63
    const unsigned b   = blockIdx.y;     // batch 0..15
    const unsigned tid = threadIdx.x;    // 0..511

    const int      base_i4 = (int)(fg * FRAMES_PB * 128u) - PREFIX4;
    const unsigned in_base = b * T4_PER_B;

    // Phase 1: one long read burst into LDS (9 strided passes, last partial).
    for (unsigned idx = tid; idx < (unsigned)WIN4; idx += 512u) {
        int i4 = base_i4 + (int)idx;
        f4 v = (f4){0.f, 0.f, 0.f, 0.f};
        if (i4 >= 0) {                    // only fg==0 touches zero prefix
            v = x4[in_base + (unsigned)i4];
        }
        lds[idx] = v;
    }
    __syncthreads();

    // Phase 2: one long sequential write burst (256 KB).
    const unsigned out_base = b * (2048u * 512u) + fg * OUT4_PB;
#pragma unroll
    for (int s = 0; s < 32; ++s) {
        unsigned o  = tid + 512u * (unsigned)s;  // local f4 idx 0..16383
        unsigned fl = o >> 9;                    // local frame 0..31
        unsigned t4 = o & 511u;                  // f4 within frame
        out4[out_base + o] = lds[fl * 128u + t4];
    }
}

extern "C" void kernel_launch(void* const* d_in, const int* in_sizes, int n_in,
                              void* d_out, int out_size, void* d_ws, size_t ws_size,
                              hipStream_t stream) {
    const f4* x4 = (const f4*)d_in[0];
    f4* out4 = (f4*)d_out;
    dim3 block(512);
    dim3 grid(64, 16);    // 2048 frames / 32 per block, 16 batches
    frame_lds32<<<grid, block, 0, stream>>>(x4, out4);
}